// Round 1
// baseline (760.677 us; speedup 1.0000x reference)
//
#include <hip/hip_runtime.h>

// Problem dims (compile-time constants from the reference)
static constexpr int L   = 1024;   // L_IN == L_ENC
static constexpr int B   = 16;
static constexpr int D   = 512;    // D_IN == D_ENC == D_EMB
static constexpr int RB  = L * B;  // 16384 rows (l,b)
static constexpr int LDR = B * D;  // 8192: stride between row l and l+1 at fixed b

#define BM 64
#define BN 64
#define BKT 16
#define PAD 4

// ---------------------------------------------------------------------------
// Kernel 1: d_vals[r,e] = sum_i X[r,i]W1[e,i] + sum_m T[r,m]W2[e,m] + b1[e]+b2[e]
// A row-major k-contiguous (transpose into LDS), W row-major [n][k] (transpose).
// ---------------------------------------------------------------------------
__global__ __launch_bounds__(256) void dvals_kernel(
    const float* __restrict__ X, const float* __restrict__ T,
    const float* __restrict__ W1, const float* __restrict__ W2,
    const float* __restrict__ b1, const float* __restrict__ b2,
    float* __restrict__ C)
{
    __shared__ float As[BKT][BM + PAD];
    __shared__ float Bs[BKT][BN + PAD];
    const int tid = threadIdx.x;
    const int tx = tid % 16, ty = tid / 16;
    const int row0 = blockIdx.y * BM;
    const int col0 = blockIdx.x * BN;
    const int lm  = tid % 64;
    const int lk4 = (tid / 64) * 4;

    float acc[4][4] = {};

    for (int phase = 0; phase < 2; ++phase) {
        const float* A = phase ? T : X;
        const float* W = phase ? W2 : W1;
        for (int kt = 0; kt < D; kt += BKT) {
            __syncthreads();
            float4 av = *(const float4*)&A[(row0 + lm) * D + kt + lk4];
            float4 bv = *(const float4*)&W[(col0 + lm) * D + kt + lk4];
            As[lk4+0][lm]=av.x; As[lk4+1][lm]=av.y; As[lk4+2][lm]=av.z; As[lk4+3][lm]=av.w;
            Bs[lk4+0][lm]=bv.x; Bs[lk4+1][lm]=bv.y; Bs[lk4+2][lm]=bv.z; Bs[lk4+3][lm]=bv.w;
            __syncthreads();
            #pragma unroll
            for (int k = 0; k < BKT; ++k) {
                float4 a = *(const float4*)&As[k][ty*4];
                float4 b = *(const float4*)&Bs[k][tx*4];
                float af[4] = {a.x,a.y,a.z,a.w};
                float bf[4] = {b.x,b.y,b.z,b.w};
                #pragma unroll
                for (int i = 0; i < 4; ++i)
                    #pragma unroll
                    for (int j = 0; j < 4; ++j)
                        acc[i][j] += af[i] * bf[j];
            }
        }
    }
    const int n0 = col0 + tx * 4;
    float bias[4];
    #pragma unroll
    for (int j = 0; j < 4; ++j) bias[j] = b1[n0+j] + b2[n0+j];
    #pragma unroll
    for (int i = 0; i < 4; ++i) {
        int r = row0 + ty * 4 + i;
        float4 o;
        o.x = acc[i][0] + bias[0];
        o.y = acc[i][1] + bias[1];
        o.z = acc[i][2] + bias[2];
        o.w = acc[i][3] + bias[3];
        *(float4*)&C[r * D + n0] = o;
    }
}

// ---------------------------------------------------------------------------
// Kernel 2: encsum[b*D+e] = sum_m enc[m,b,e]   (t == b*D+e directly)
// ---------------------------------------------------------------------------
__global__ __launch_bounds__(256) void encsum_kernel(
    const float* __restrict__ E, float* __restrict__ out)
{
    int t = blockIdx.x * blockDim.x + threadIdx.x;  // 0 .. B*D-1
    float acc = 0.f;
    for (int m = 0; m < L; ++m) acc += E[m * LDR + t];
    out[t] = acc;
}

// ---------------------------------------------------------------------------
// Kernel 3: G_b[e1,e2] = sum_m Enc_b[m,e1] * Enc_b[m,e2]  (both direct k-major)
// ---------------------------------------------------------------------------
__global__ __launch_bounds__(256) void gram_kernel(
    const float* __restrict__ E, float* __restrict__ G)
{
    __shared__ float As[BKT][BM + PAD];
    __shared__ float Bs[BKT][BN + PAD];
    const int b = blockIdx.z;
    const int tid = threadIdx.x;
    const int tx = tid % 16, ty = tid / 16;
    const int row0 = blockIdx.y * BM;   // e1
    const int col0 = blockIdx.x * BN;   // e2
    const float* Eb = E + b * D;        // row m at Eb[m*LDR + e]
    const int ln4 = (tid % 16) * 4;
    const int lkk = tid / 16;

    float acc[4][4] = {};

    for (int kt = 0; kt < L; kt += BKT) {
        __syncthreads();
        float4 av = *(const float4*)&Eb[(kt + lkk) * LDR + row0 + ln4];
        float4 bv = *(const float4*)&Eb[(kt + lkk) * LDR + col0 + ln4];
        *(float4*)&As[lkk][ln4] = av;
        *(float4*)&Bs[lkk][ln4] = bv;
        __syncthreads();
        #pragma unroll
        for (int k = 0; k < BKT; ++k) {
            float4 a = *(const float4*)&As[k][ty*4];
            float4 b2v = *(const float4*)&Bs[k][tx*4];
            float af[4] = {a.x,a.y,a.z,a.w};
            float bf[4] = {b2v.x,b2v.y,b2v.z,b2v.w};
            #pragma unroll
            for (int i = 0; i < 4; ++i)
                #pragma unroll
                for (int j = 0; j < 4; ++j)
                    acc[i][j] += af[i] * bf[j];
        }
    }
    float* Gb = G + b * D * D;
    #pragma unroll
    for (int i = 0; i < 4; ++i) {
        float4 o; o.x = acc[i][0]; o.y = acc[i][1]; o.z = acc[i][2]; o.w = acc[i][3];
        *(float4*)&Gb[(row0 + ty*4 + i) * D + col0 + tx*4] = o;
    }
}

// ---------------------------------------------------------------------------
// Kernel 4: S[r] = sum_e dvals[r,e] * encsum[(r%16)*D + e]   (one wave per row)
// ---------------------------------------------------------------------------
__global__ __launch_bounds__(256) void s_kernel(
    const float* __restrict__ Dv, const float* __restrict__ encsum,
    float* __restrict__ S)
{
    const int wave = threadIdx.x / 64, lane = threadIdx.x % 64;
    const int r = blockIdx.x * 4 + wave;
    const float* row = Dv + r * D;
    const float* es  = encsum + (r % B) * D;
    float acc = 0.f;
    for (int e = lane * 4; e < D; e += 256) {
        float4 d = *(const float4*)&row[e];
        float4 s = *(const float4*)&es[e];
        acc += d.x*s.x + d.y*s.y + d.z*s.z + d.w*s.w;
    }
    #pragma unroll
    for (int off = 32; off > 0; off >>= 1) acc += __shfl_down(acc, off, 64);
    if (lane == 0) S[r] = acc;
}

// ---------------------------------------------------------------------------
// Kernel 5: numer[l,b,e] = sum_{e'} dvals[l,b,e'] * G_b[e',e]
// A: dvals rows at b*D + l*LDR (k-contiguous -> transpose), B: G_b direct.
// ---------------------------------------------------------------------------
__global__ __launch_bounds__(256) void numer_kernel(
    const float* __restrict__ Dv, const float* __restrict__ G,
    float* __restrict__ Nout)
{
    __shared__ float As[BKT][BM + PAD];
    __shared__ float Bs[BKT][BN + PAD];
    const int b = blockIdx.z;
    const int tid = threadIdx.x;
    const int tx = tid % 16, ty = tid / 16;
    const int row0 = blockIdx.y * BM;   // l
    const int col0 = blockIdx.x * BN;   // e
    const float* A  = Dv + b * D;       // row l at A[l*LDR + e']
    const float* Gb = G + b * D * D;
    const int lm  = tid % 64;
    const int lk4 = (tid / 64) * 4;
    const int ln4 = (tid % 16) * 4;
    const int lkk = tid / 16;

    float acc[4][4] = {};

    for (int kt = 0; kt < D; kt += BKT) {
        __syncthreads();
        float4 av = *(const float4*)&A[(row0 + lm) * LDR + kt + lk4];
        float4 bv = *(const float4*)&Gb[(kt + lkk) * D + col0 + ln4];
        As[lk4+0][lm]=av.x; As[lk4+1][lm]=av.y; As[lk4+2][lm]=av.z; As[lk4+3][lm]=av.w;
        *(float4*)&Bs[lkk][ln4] = bv;
        __syncthreads();
        #pragma unroll
        for (int k = 0; k < BKT; ++k) {
            float4 a = *(const float4*)&As[k][ty*4];
            float4 b2v = *(const float4*)&Bs[k][tx*4];
            float af[4] = {a.x,a.y,a.z,a.w};
            float bf[4] = {b2v.x,b2v.y,b2v.z,b2v.w};
            #pragma unroll
            for (int i = 0; i < 4; ++i)
                #pragma unroll
                for (int j = 0; j < 4; ++j)
                    acc[i][j] += af[i] * bf[j];
        }
    }
    #pragma unroll
    for (int i = 0; i < 4; ++i) {
        int l = row0 + ty * 4 + i;
        float4 o; o.x = acc[i][0]; o.y = acc[i][1]; o.z = acc[i][2]; o.w = acc[i][3];
        *(float4*)&Nout[l * LDR + b * D + col0 + tx*4] = o;
    }
}

// ---------------------------------------------------------------------------
// Kernel 6: out[r,i] = (sum_e numer[r,e] * W3[i,e]) / S[r] + b3[i]
// ---------------------------------------------------------------------------
__global__ __launch_bounds__(256) void out_kernel(
    const float* __restrict__ Nm, const float* __restrict__ W3,
    const float* __restrict__ b3, const float* __restrict__ S,
    float* __restrict__ O)
{
    __shared__ float As[BKT][BM + PAD];
    __shared__ float Bs[BKT][BN + PAD];
    const int tid = threadIdx.x;
    const int tx = tid % 16, ty = tid / 16;
    const int row0 = blockIdx.y * BM;
    const int col0 = blockIdx.x * BN;
    const int lm  = tid % 64;
    const int lk4 = (tid / 64) * 4;

    float acc[4][4] = {};

    for (int kt = 0; kt < D; kt += BKT) {
        __syncthreads();
        float4 av = *(const float4*)&Nm[(row0 + lm) * D + kt + lk4];
        float4 bv = *(const float4*)&W3[(col0 + lm) * D + kt + lk4];
        As[lk4+0][lm]=av.x; As[lk4+1][lm]=av.y; As[lk4+2][lm]=av.z; As[lk4+3][lm]=av.w;
        Bs[lk4+0][lm]=bv.x; Bs[lk4+1][lm]=bv.y; Bs[lk4+2][lm]=bv.z; Bs[lk4+3][lm]=bv.w;
        __syncthreads();
        #pragma unroll
        for (int k = 0; k < BKT; ++k) {
            float4 a = *(const float4*)&As[k][ty*4];
            float4 b2v = *(const float4*)&Bs[k][tx*4];
            float af[4] = {a.x,a.y,a.z,a.w};
            float bf[4] = {b2v.x,b2v.y,b2v.z,b2v.w};
            #pragma unroll
            for (int i = 0; i < 4; ++i)
                #pragma unroll
                for (int j = 0; j < 4; ++j)
                    acc[i][j] += af[i] * bf[j];
        }
    }
    const int n0 = col0 + tx * 4;
    float bias[4];
    #pragma unroll
    for (int j = 0; j < 4; ++j) bias[j] = b3[n0+j];
    #pragma unroll
    for (int i = 0; i < 4; ++i) {
        int r = row0 + ty * 4 + i;
        float inv = 1.0f / S[r];
        float4 o;
        o.x = acc[i][0] * inv + bias[0];
        o.y = acc[i][1] * inv + bias[1];
        o.z = acc[i][2] * inv + bias[2];
        o.w = acc[i][3] * inv + bias[3];
        *(float4*)&O[r * D + n0] = o;
    }
}

extern "C" void kernel_launch(void* const* d_in, const int* in_sizes, int n_in,
                              void* d_out, int out_size, void* d_ws, size_t ws_size,
                              hipStream_t stream)
{
    const float* in_seq  = (const float*)d_in[0];
    const float* enc_seq = (const float*)d_in[1];
    const float* prev    = (const float*)d_in[2];
    const float* W1      = (const float*)d_in[3];
    const float* b1      = (const float*)d_in[4];
    const float* W2      = (const float*)d_in[5];
    const float* b2      = (const float*)d_in[6];
    const float* W3      = (const float*)d_in[7];
    const float* b3      = (const float*)d_in[8];
    float* out = (float*)d_out;

    float* dvals  = (float*)d_ws;            // 16384*512
    float* gram   = dvals  + RB * D;         // 16*512*512
    float* numer  = gram   + B * D * D;      // 16384*512
    float* encsum = numer  + RB * D;         // 16*512
    float* S      = encsum + B * D;          // 16384
    // total ~84 MB of ws

    dim3 blk(256);
    dvals_kernel <<<dim3(D/BN, RB/BM),    blk, 0, stream>>>(in_seq, prev, W1, W2, b1, b2, dvals);
    encsum_kernel<<<dim3(B*D/256),        blk, 0, stream>>>(enc_seq, encsum);
    gram_kernel  <<<dim3(D/BN, D/BM, B),  blk, 0, stream>>>(enc_seq, gram);
    s_kernel     <<<dim3(RB/4),           blk, 0, stream>>>(dvals, encsum, S);
    numer_kernel <<<dim3(D/BN, L/BM, B),  blk, 0, stream>>>(dvals, gram, numer);
    out_kernel   <<<dim3(D/BN, RB/BM),    blk, 0, stream>>>(numer, W3, b3, S, out);
}

// Round 2
// 747.772 us; speedup vs baseline: 1.0173x; 1.0173x over previous
//
#include <hip/hip_runtime.h>

static constexpr int L   = 1024;
static constexpr int B   = 16;
static constexpr int D   = 512;
static constexpr int RB  = L * B;    // 16384
static constexpr int LDR = B * D;    // 8192 floats between consecutive l

#define TBM 128
#define TBN 128
#define TBK 16
#define LDT 132   // padded LDS row (132*4B = 528B, multiple of 16B)

// 16-k-step FMA block on staged tiles; 8x8 microtile per thread.
__device__ __forceinline__ void compute_tile(
    const float (*As)[LDT], const float (*Bs)[LDT],
    float acc[8][8], int tx4, int ty4)
{
    #pragma unroll
    for (int k = 0; k < TBK; ++k) {
        float4 a0 = *(const float4*)&As[k][ty4];
        float4 a1 = *(const float4*)&As[k][ty4 + 64];
        float4 b0 = *(const float4*)&Bs[k][tx4];
        float4 b1 = *(const float4*)&Bs[k][tx4 + 64];
        float av[8] = {a0.x,a0.y,a0.z,a0.w,a1.x,a1.y,a1.z,a1.w};
        float bv[8] = {b0.x,b0.y,b0.z,b0.w,b1.x,b1.y,b1.z,b1.w};
        #pragma unroll
        for (int i = 0; i < 8; ++i)
            #pragma unroll
            for (int j = 0; j < 8; ++j)
                acc[i][j] += av[i] * bv[j];
    }
}

// ---------------------------------------------------------------------------
// Kernel 1: dvals = X·W1^T + T·W2^T + b1 + b2   (A,B both k-contiguous rows)
// K = 1024 total (two 512 phases). Grid (D/128, RB/128).
// ---------------------------------------------------------------------------
__global__ __launch_bounds__(256) void dvals_kernel(
    const float* __restrict__ X, const float* __restrict__ T,
    const float* __restrict__ W1, const float* __restrict__ W2,
    const float* __restrict__ b1, const float* __restrict__ b2,
    float* __restrict__ C)
{
    __shared__ float As[TBK][LDT];
    __shared__ float Bs[TBK][LDT];
    const int tid  = threadIdx.x;
    const int row0 = blockIdx.y * TBM;
    const int col0 = blockIdx.x * TBN;
    const int lr0 = tid >> 2;          // 0..63
    const int lk0 = (tid & 3) * 4;     // 0,4,8,12
    const int tx4 = (tid & 15) * 4;
    const int ty4 = (tid >> 4) * 4;

    float acc[8][8] = {};
    float4 pa[2], pb[2];

    pa[0] = *(const float4*)&X[(row0 + lr0)      * D + lk0];
    pa[1] = *(const float4*)&X[(row0 + lr0 + 64) * D + lk0];
    pb[0] = *(const float4*)&W1[(col0 + lr0)      * D + lk0];
    pb[1] = *(const float4*)&W1[(col0 + lr0 + 64) * D + lk0];

    for (int it = 0; it < 64; ++it) {
        #pragma unroll
        for (int q = 0; q < 2; ++q) {
            int r = lr0 + q * 64;
            As[lk0+0][r] = pa[q].x; As[lk0+1][r] = pa[q].y;
            As[lk0+2][r] = pa[q].z; As[lk0+3][r] = pa[q].w;
            Bs[lk0+0][r] = pb[q].x; Bs[lk0+1][r] = pb[q].y;
            Bs[lk0+2][r] = pb[q].z; Bs[lk0+3][r] = pb[q].w;
        }
        __syncthreads();
        if (it + 1 < 64) {
            int nit = it + 1;
            const float* A = (nit < 32) ? X : T;
            const float* W = (nit < 32) ? W1 : W2;
            int kt = (nit & 31) * TBK;
            pa[0] = *(const float4*)&A[(row0 + lr0)      * D + kt + lk0];
            pa[1] = *(const float4*)&A[(row0 + lr0 + 64) * D + kt + lk0];
            pb[0] = *(const float4*)&W[(col0 + lr0)      * D + kt + lk0];
            pb[1] = *(const float4*)&W[(col0 + lr0 + 64) * D + kt + lk0];
        }
        compute_tile(As, Bs, acc, tx4, ty4);
        __syncthreads();
    }

    float bias[8];
    #pragma unroll
    for (int j = 0; j < 4; ++j) {
        bias[j]     = b1[col0 + tx4 + j]      + b2[col0 + tx4 + j];
        bias[4 + j] = b1[col0 + tx4 + 64 + j] + b2[col0 + tx4 + 64 + j];
    }
    #pragma unroll
    for (int i = 0; i < 8; ++i) {
        int r = row0 + ((i < 4) ? (ty4 + i) : (ty4 + i + 60));
        float4 o0 = {acc[i][0]+bias[0], acc[i][1]+bias[1], acc[i][2]+bias[2], acc[i][3]+bias[3]};
        float4 o1 = {acc[i][4]+bias[4], acc[i][5]+bias[5], acc[i][6]+bias[6], acc[i][7]+bias[7]};
        *(float4*)&C[r * D + col0 + tx4]      = o0;
        *(float4*)&C[r * D + col0 + tx4 + 64] = o1;
    }
}

// ---------------------------------------------------------------------------
// Kernel 2/3: encsum (two-stage for parallelism)
// ---------------------------------------------------------------------------
__global__ __launch_bounds__(256) void encsum_partial_kernel(
    const float* __restrict__ E, float* __restrict__ partial)
{
    int t  = blockIdx.x * 256 + threadIdx.x;   // 0..8191
    int cy = blockIdx.y;                        // 0..7
    float acc = 0.f;
    for (int m = 0; m < 128; ++m) acc += E[(cy * 128 + m) * LDR + t];
    partial[cy * LDR + t] = acc;
}

__global__ __launch_bounds__(256) void encsum_final_kernel(
    const float* __restrict__ partial, float* __restrict__ out)
{
    int t = blockIdx.x * 256 + threadIdx.x;
    float acc = 0.f;
    #pragma unroll
    for (int c = 0; c < 8; ++c) acc += partial[c * LDR + t];
    out[t] = acc;
}

// ---------------------------------------------------------------------------
// Kernel 4: P[b][m][i] = sum_e Enc[m,b,e] * W3[i,e]   (both k-contiguous)
// Grid (D/128, L/128, B). K = 512.
// ---------------------------------------------------------------------------
__global__ __launch_bounds__(256) void p_kernel(
    const float* __restrict__ E, const float* __restrict__ W3,
    float* __restrict__ P)
{
    __shared__ float As[TBK][LDT];
    __shared__ float Bs[TBK][LDT];
    const int b    = blockIdx.z;
    const int tid  = threadIdx.x;
    const int row0 = blockIdx.y * TBM;   // m
    const int col0 = blockIdx.x * TBN;   // i
    const int lr0 = tid >> 2;
    const int lk0 = (tid & 3) * 4;
    const int tx4 = (tid & 15) * 4;
    const int ty4 = (tid >> 4) * 4;

    float acc[8][8] = {};
    float4 pa[2], pb[2];

    pa[0] = *(const float4*)&E[(row0 + lr0)      * LDR + b * D + lk0];
    pa[1] = *(const float4*)&E[(row0 + lr0 + 64) * LDR + b * D + lk0];
    pb[0] = *(const float4*)&W3[(col0 + lr0)      * D + lk0];
    pb[1] = *(const float4*)&W3[(col0 + lr0 + 64) * D + lk0];

    for (int it = 0; it < 32; ++it) {
        #pragma unroll
        for (int q = 0; q < 2; ++q) {
            int r = lr0 + q * 64;
            As[lk0+0][r] = pa[q].x; As[lk0+1][r] = pa[q].y;
            As[lk0+2][r] = pa[q].z; As[lk0+3][r] = pa[q].w;
            Bs[lk0+0][r] = pb[q].x; Bs[lk0+1][r] = pb[q].y;
            Bs[lk0+2][r] = pb[q].z; Bs[lk0+3][r] = pb[q].w;
        }
        __syncthreads();
        if (it + 1 < 32) {
            int kt = (it + 1) * TBK;
            pa[0] = *(const float4*)&E[(row0 + lr0)      * LDR + b * D + kt + lk0];
            pa[1] = *(const float4*)&E[(row0 + lr0 + 64) * LDR + b * D + kt + lk0];
            pb[0] = *(const float4*)&W3[(col0 + lr0)      * D + kt + lk0];
            pb[1] = *(const float4*)&W3[(col0 + lr0 + 64) * D + kt + lk0];
        }
        compute_tile(As, Bs, acc, tx4, ty4);
        __syncthreads();
    }

    float* Pb = P + b * (L * D);
    #pragma unroll
    for (int i = 0; i < 8; ++i) {
        int r = row0 + ((i < 4) ? (ty4 + i) : (ty4 + i + 60));
        float4 o0 = {acc[i][0], acc[i][1], acc[i][2], acc[i][3]};
        float4 o1 = {acc[i][4], acc[i][5], acc[i][6], acc[i][7]};
        *(float4*)&Pb[r * D + col0 + tx4]      = o0;
        *(float4*)&Pb[r * D + col0 + tx4 + 64] = o1;
    }
}

// ---------------------------------------------------------------------------
// Kernel 5: H[b][e1][i] = sum_m Enc[m,b,e1] * P[b][m][i]  (both n-contiguous)
// Grid (D/128, D/128, B). K = 1024.
// ---------------------------------------------------------------------------
__global__ __launch_bounds__(256) void h_kernel(
    const float* __restrict__ E, const float* __restrict__ P,
    float* __restrict__ H)
{
    __shared__ float As[TBK][LDT];
    __shared__ float Bs[TBK][LDT];
    const int b    = blockIdx.z;
    const int tid  = threadIdx.x;
    const int row0 = blockIdx.y * TBM;   // e1
    const int col0 = blockIdx.x * TBN;   // i
    const int mi0 = tid >> 5;            // 0..7  (q=1 adds 8)
    const int e16 = (tid & 31) * 4;      // 0..124
    const int tx4 = (tid & 15) * 4;
    const int ty4 = (tid >> 4) * 4;
    const float* Pb = P + b * (L * D);

    float acc[8][8] = {};
    float4 pa[2], pb[2];

    pa[0] = *(const float4*)&E[(mi0)     * LDR + b * D + row0 + e16];
    pa[1] = *(const float4*)&E[(mi0 + 8) * LDR + b * D + row0 + e16];
    pb[0] = *(const float4*)&Pb[(mi0)     * D + col0 + e16];
    pb[1] = *(const float4*)&Pb[(mi0 + 8) * D + col0 + e16];

    for (int it = 0; it < 64; ++it) {
        *(float4*)&As[mi0][e16]     = pa[0];
        *(float4*)&As[mi0 + 8][e16] = pa[1];
        *(float4*)&Bs[mi0][e16]     = pb[0];
        *(float4*)&Bs[mi0 + 8][e16] = pb[1];
        __syncthreads();
        if (it + 1 < 64) {
            int kt = (it + 1) * TBK;
            pa[0] = *(const float4*)&E[(kt + mi0)     * LDR + b * D + row0 + e16];
            pa[1] = *(const float4*)&E[(kt + mi0 + 8) * LDR + b * D + row0 + e16];
            pb[0] = *(const float4*)&Pb[(kt + mi0)     * D + col0 + e16];
            pb[1] = *(const float4*)&Pb[(kt + mi0 + 8) * D + col0 + e16];
        }
        compute_tile(As, Bs, acc, tx4, ty4);
        __syncthreads();
    }

    float* Hb = H + b * (D * D);
    #pragma unroll
    for (int i = 0; i < 8; ++i) {
        int r = row0 + ((i < 4) ? (ty4 + i) : (ty4 + i + 60));
        float4 o0 = {acc[i][0], acc[i][1], acc[i][2], acc[i][3]};
        float4 o1 = {acc[i][4], acc[i][5], acc[i][6], acc[i][7]};
        *(float4*)&Hb[r * D + col0 + tx4]      = o0;
        *(float4*)&Hb[r * D + col0 + tx4 + 64] = o1;
    }
}

// ---------------------------------------------------------------------------
// Kernel 6: S[r] = sum_e dvals[r,e] * encsum[(r%16)*D + e]
// ---------------------------------------------------------------------------
__global__ __launch_bounds__(256) void s_kernel(
    const float* __restrict__ Dv, const float* __restrict__ encsum,
    float* __restrict__ S)
{
    const int wave = threadIdx.x / 64, lane = threadIdx.x % 64;
    const int r = blockIdx.x * 4 + wave;
    const float* row = Dv + r * D;
    const float* es  = encsum + (r % B) * D;
    float acc = 0.f;
    for (int e = lane * 4; e < D; e += 256) {
        float4 d = *(const float4*)&row[e];
        float4 s = *(const float4*)&es[e];
        acc += d.x*s.x + d.y*s.y + d.z*s.z + d.w*s.w;
    }
    #pragma unroll
    for (int off = 32; off > 0; off >>= 1) acc += __shfl_down(acc, off, 64);
    if (lane == 0) S[r] = acc;
}

// ---------------------------------------------------------------------------
// Kernel 7: out[l,b,i] = (sum_e dvals[l,b,e] * H[b][e][i]) / S[l*16+b] + b3[i]
// A k-contiguous (transpose-load), B n-contiguous (direct). Grid (4, 8, 16).
// ---------------------------------------------------------------------------
__global__ __launch_bounds__(256) void out_kernel(
    const float* __restrict__ Dv, const float* __restrict__ H,
    const float* __restrict__ b3, const float* __restrict__ S,
    float* __restrict__ O)
{
    __shared__ float As[TBK][LDT];
    __shared__ float Bs[TBK][LDT];
    const int b    = blockIdx.z;
    const int tid  = threadIdx.x;
    const int row0 = blockIdx.y * TBM;   // l
    const int col0 = blockIdx.x * TBN;   // i
    const int lr0 = tid >> 2;
    const int lk0 = (tid & 3) * 4;
    const int mi0 = tid >> 5;
    const int e16 = (tid & 31) * 4;
    const int tx4 = (tid & 15) * 4;
    const int ty4 = (tid >> 4) * 4;
    const float* Hb = H + b * (D * D);

    float acc[8][8] = {};
    float4 pa[2], pb[2];

    pa[0] = *(const float4*)&Dv[(row0 + lr0)      * LDR + b * D + lk0];
    pa[1] = *(const float4*)&Dv[(row0 + lr0 + 64) * LDR + b * D + lk0];
    pb[0] = *(const float4*)&Hb[(mi0)     * D + col0 + e16];
    pb[1] = *(const float4*)&Hb[(mi0 + 8) * D + col0 + e16];

    for (int it = 0; it < 32; ++it) {
        #pragma unroll
        for (int q = 0; q < 2; ++q) {
            int r = lr0 + q * 64;
            As[lk0+0][r] = pa[q].x; As[lk0+1][r] = pa[q].y;
            As[lk0+2][r] = pa[q].z; As[lk0+3][r] = pa[q].w;
        }
        *(float4*)&Bs[mi0][e16]     = pb[0];
        *(float4*)&Bs[mi0 + 8][e16] = pb[1];
        __syncthreads();
        if (it + 1 < 32) {
            int kt = (it + 1) * TBK;
            pa[0] = *(const float4*)&Dv[(row0 + lr0)      * LDR + b * D + kt + lk0];
            pa[1] = *(const float4*)&Dv[(row0 + lr0 + 64) * LDR + b * D + kt + lk0];
            pb[0] = *(const float4*)&Hb[(kt + mi0)     * D + col0 + e16];
            pb[1] = *(const float4*)&Hb[(kt + mi0 + 8) * D + col0 + e16];
        }
        compute_tile(As, Bs, acc, tx4, ty4);
        __syncthreads();
    }

    float bias[8];
    #pragma unroll
    for (int j = 0; j < 4; ++j) {
        bias[j]     = b3[col0 + tx4 + j];
        bias[4 + j] = b3[col0 + tx4 + 64 + j];
    }
    #pragma unroll
    for (int i = 0; i < 8; ++i) {
        int l = row0 + ((i < 4) ? (ty4 + i) : (ty4 + i + 60));
        float inv = 1.0f / S[l * B + b];
        float4 o0 = {acc[i][0]*inv+bias[0], acc[i][1]*inv+bias[1],
                     acc[i][2]*inv+bias[2], acc[i][3]*inv+bias[3]};
        float4 o1 = {acc[i][4]*inv+bias[4], acc[i][5]*inv+bias[5],
                     acc[i][6]*inv+bias[6], acc[i][7]*inv+bias[7]};
        *(float4*)&O[l * LDR + b * D + col0 + tx4]      = o0;
        *(float4*)&O[l * LDR + b * D + col0 + tx4 + 64] = o1;
    }
}

extern "C" void kernel_launch(void* const* d_in, const int* in_sizes, int n_in,
                              void* d_out, int out_size, void* d_ws, size_t ws_size,
                              hipStream_t stream)
{
    const float* in_seq  = (const float*)d_in[0];
    const float* enc_seq = (const float*)d_in[1];
    const float* prev    = (const float*)d_in[2];
    const float* W1      = (const float*)d_in[3];
    const float* b1      = (const float*)d_in[4];
    const float* W2      = (const float*)d_in[5];
    const float* b2      = (const float*)d_in[6];
    const float* W3      = (const float*)d_in[7];
    const float* b3      = (const float*)d_in[8];
    float* out = (float*)d_out;

    float* dvals   = (float*)d_ws;             // 16384*512      (32 MB)
    float* P       = dvals   + RB * D;         // 16*1024*512    (32 MB)
    float* H       = P       + B * L * D;      // 16*512*512     (16 MB)
    float* partial = H       + B * D * D;      // 8*8192
    float* encsum  = partial + 8 * LDR;        // 8192
    float* S       = encsum  + LDR;            // 16384

    dim3 blk(256);
    dvals_kernel        <<<dim3(D/TBN, RB/TBM),     blk, 0, stream>>>(in_seq, prev, W1, W2, b1, b2, dvals);
    encsum_partial_kernel<<<dim3(LDR/256, 8),       blk, 0, stream>>>(enc_seq, partial);
    encsum_final_kernel <<<dim3(LDR/256),           blk, 0, stream>>>(partial, encsum);
    p_kernel            <<<dim3(D/TBN, L/TBM, B),   blk, 0, stream>>>(enc_seq, W3, P);
    h_kernel            <<<dim3(D/TBN, D/TBM, B),   blk, 0, stream>>>(enc_seq, P, H);
    s_kernel            <<<dim3(RB/4),              blk, 0, stream>>>(dvals, encsum, S);
    out_kernel          <<<dim3(D/TBN, L/TBM, B),   blk, 0, stream>>>(dvals, H, b3, S, out);
}

// Round 3
// 304.724 us; speedup vs baseline: 2.4963x; 2.4539x over previous
//
#include <hip/hip_runtime.h>
#include <cstdint>

static constexpr int L   = 1024;
static constexpr int B   = 16;
static constexpr int D   = 512;
static constexpr int RB  = L * B;    // 16384
static constexpr int LDR = B * D;    // 8192

typedef uint16_t u16;
typedef __attribute__((ext_vector_type(8))) short short8;
typedef __attribute__((ext_vector_type(4))) float f32x4;
struct alignas(8) U16x4 { u16 x, y, z, w; };

__device__ __forceinline__ u16 f2bf(float f) {
    union { float f; unsigned u; } v; v.f = f;
    unsigned r = v.u + 0x7fffu + ((v.u >> 16) & 1u);
    return (u16)(r >> 16);
}

template<bool F32>
__device__ __forceinline__ short8 load_chunk(const void* p) {
    if constexpr (F32) {
        const float4 a = *(const float4*)p;
        const float4 b = *((const float4*)p + 1);
        short8 r;
        r[0]=(short)f2bf(a.x); r[1]=(short)f2bf(a.y); r[2]=(short)f2bf(a.z); r[3]=(short)f2bf(a.w);
        r[4]=(short)f2bf(b.x); r[5]=(short)f2bf(b.y); r[6]=(short)f2bf(b.z); r[7]=(short)f2bf(b.w);
        return r;
    } else {
        return *(const short8*)p;
    }
}

// MODE 1: dvals[r][e]  A=X|T (fp32, lda 512, K=1024 two phases)  B=W1|W2
// MODE 2: PT[b][i][m]  A=W3 (fp32, 512)   B=Enc rows m (fp32, ld 8192), N=1024
// MODE 3: HT[b][i][e1] A=PT_bf (1024)     B=EncT_bf (1024)
// MODE 4: out[l,b,i]   A=dvals_bf (ld 8192, base z*512)  B=HT_bf (512)
template<int MODE>
__device__ __forceinline__ const void* a_chunk_ptr(
    const float* Xp, const float* Tp, const float* W3,
    const u16* PT_c, const u16* dvals_c, int row, int kk, int z)
{
    if constexpr (MODE == 1) {
        return (kk < 512) ? (const void*)(Xp + row*512 + kk)
                          : (const void*)(Tp + row*512 + kk - 512);
    } else if constexpr (MODE == 2) {
        return W3 + row*512 + kk;
    } else if constexpr (MODE == 3) {
        return PT_c + z*524288 + row*1024 + kk;
    } else {
        return dvals_c + (row*16 + z)*512 + kk;
    }
}
template<int MODE>
__device__ __forceinline__ const void* b_chunk_ptr(
    const float* W1, const float* W2, const float* Enc,
    const u16* EncT_c, const u16* HT_c, int row, int kk, int z)
{
    if constexpr (MODE == 1) {
        return (kk < 512) ? (const void*)(W1 + row*512 + kk)
                          : (const void*)(W2 + row*512 + kk - 512);
    } else if constexpr (MODE == 2) {
        return Enc + row*8192 + z*512 + kk;
    } else if constexpr (MODE == 3) {
        return EncT_c + z*524288 + row*1024 + kk;
    } else {
        return HT_c + z*262144 + row*512 + kk;
    }
}

template<int MODE>
__global__ __launch_bounds__(256) void gemm_bf16(
    const float* __restrict__ Xp, const float* __restrict__ Tp,
    const float* __restrict__ W1, const float* __restrict__ W2,
    const float* __restrict__ W3, const float* __restrict__ Enc,
    const float* __restrict__ b1, const float* __restrict__ b2,
    const float* __restrict__ b3, const float* __restrict__ Sinv,
    const u16* __restrict__ dvals_c, const u16* __restrict__ PT_c,
    const u16* __restrict__ EncT_c, const u16* __restrict__ HT_c,
    u16* __restrict__ Cb, float* __restrict__ Cf)
{
    constexpr int K = (MODE == 2 || MODE == 4) ? 512 : 1024;
    constexpr bool F32S = (MODE <= 2);
    __shared__ __align__(16) u16 As[128 * 40];
    __shared__ __align__(16) u16 Bs[128 * 40];
    const int z    = blockIdx.z;
    const int row0 = blockIdx.y * 128;
    const int col0 = blockIdx.x * 128;
    const int tid  = threadIdx.x;
    const int lane = tid & 63, w = tid >> 6;
    const int wm = w >> 1, wn = w & 1;
    const int quad = lane >> 4, l16 = lane & 15;
    const int crow = tid >> 2, ck8 = (tid & 3) * 8;

    f32x4 acc[4][4] = {};
    short8 pa0, pa1, pb0, pb1;
    pa0 = load_chunk<F32S>(a_chunk_ptr<MODE>(Xp,Tp,W3,PT_c,dvals_c, row0+crow,    ck8, z));
    pa1 = load_chunk<F32S>(a_chunk_ptr<MODE>(Xp,Tp,W3,PT_c,dvals_c, row0+crow+64, ck8, z));
    pb0 = load_chunk<F32S>(b_chunk_ptr<MODE>(W1,W2,Enc,EncT_c,HT_c, col0+crow,    ck8, z));
    pb1 = load_chunk<F32S>(b_chunk_ptr<MODE>(W1,W2,Enc,EncT_c,HT_c, col0+crow+64, ck8, z));

    for (int kb = 0; kb < K; kb += 32) {
        *(short8*)&As[crow*40 + ck8]        = pa0;
        *(short8*)&As[(crow+64)*40 + ck8]   = pa1;
        *(short8*)&Bs[crow*40 + ck8]        = pb0;
        *(short8*)&Bs[(crow+64)*40 + ck8]   = pb1;
        __syncthreads();
        if (kb + 32 < K) {
            const int kn = kb + 32 + ck8;
            pa0 = load_chunk<F32S>(a_chunk_ptr<MODE>(Xp,Tp,W3,PT_c,dvals_c, row0+crow,    kn, z));
            pa1 = load_chunk<F32S>(a_chunk_ptr<MODE>(Xp,Tp,W3,PT_c,dvals_c, row0+crow+64, kn, z));
            pb0 = load_chunk<F32S>(b_chunk_ptr<MODE>(W1,W2,Enc,EncT_c,HT_c, col0+crow,    kn, z));
            pb1 = load_chunk<F32S>(b_chunk_ptr<MODE>(W1,W2,Enc,EncT_c,HT_c, col0+crow+64, kn, z));
        }
        short8 af[4], bfr[4];
        #pragma unroll
        for (int i = 0; i < 4; ++i)
            af[i] = *(const short8*)&As[(wm*64 + i*16 + l16)*40 + quad*8];
        #pragma unroll
        for (int j = 0; j < 4; ++j)
            bfr[j] = *(const short8*)&Bs[(wn*64 + j*16 + l16)*40 + quad*8];
        #pragma unroll
        for (int i = 0; i < 4; ++i)
            #pragma unroll
            for (int j = 0; j < 4; ++j)
                acc[i][j] = __builtin_amdgcn_mfma_f32_16x16x32_bf16(af[i], bfr[j], acc[i][j], 0, 0, 0);
        __syncthreads();
    }

    #pragma unroll
    for (int i = 0; i < 4; ++i) {
        const int grow = row0 + wm*64 + i*16 + quad*4;
        #pragma unroll
        for (int j = 0; j < 4; ++j) {
            const int gcol = col0 + wn*64 + j*16 + l16;
            #pragma unroll
            for (int r = 0; r < 4; ++r) {
                float v = acc[i][j][r];
                const int R = grow + r;
                if constexpr (MODE == 1) {
                    v += b1[gcol] + b2[gcol];
                    Cb[R*512 + gcol] = f2bf(v);
                } else if constexpr (MODE == 2) {
                    Cb[z*524288 + R*1024 + gcol] = f2bf(v);
                } else if constexpr (MODE == 3) {
                    Cb[z*262144 + R*512 + gcol] = f2bf(v);
                } else {
                    const float s = Sinv[R*16 + z];
                    Cf[(R*16 + z)*512 + gcol] = v * s + b3[gcol];
                }
            }
        }
    }
}

// EncT_bf[b][e][m] <- bf16(enc[m][b][e]) via 64x64 LDS tiles
__global__ __launch_bounds__(256) void enct_kernel(
    const float* __restrict__ E, u16* __restrict__ EncT)
{
    __shared__ float tile[64][65];
    const int bb = blockIdx.z;
    const int m0 = blockIdx.y * 64;
    const int e0 = blockIdx.x * 64;
    const int t = threadIdx.x;
    const int tr = t >> 4;
    const int tc4 = (t & 15) * 4;
    #pragma unroll
    for (int it = 0; it < 4; ++it) {
        const int ml = tr + it*16;
        float4 v = *(const float4*)&E[(m0+ml)*LDR + bb*512 + e0 + tc4];
        *(float4*)&tile[ml][tc4] = v;
    }
    __syncthreads();
    #pragma unroll
    for (int it = 0; it < 4; ++it) {
        const int el = tr + it*16;
        U16x4 o;
        o.x = f2bf(tile[tc4+0][el]);
        o.y = f2bf(tile[tc4+1][el]);
        o.z = f2bf(tile[tc4+2][el]);
        o.w = f2bf(tile[tc4+3][el]);
        *(U16x4*)&EncT[bb*524288 + (e0+el)*1024 + m0 + tc4] = o;
    }
}

__global__ __launch_bounds__(256) void encsum_partial(
    const float* __restrict__ E, double* __restrict__ part)
{
    const int t  = blockIdx.x * 256 + threadIdx.x;  // b*512+e
    const int cy = blockIdx.y;
    double a = 0.0;
    for (int m = 0; m < 128; ++m) a += (double)E[(cy*128 + m)*LDR + t];
    part[cy*LDR + t] = a;
}

__global__ __launch_bounds__(256) void encsum_final(
    const double* __restrict__ part, double* __restrict__ es)
{
    const int t = blockIdx.x * 256 + threadIdx.x;
    double a = 0.0;
    #pragma unroll
    for (int c = 0; c < 8; ++c) a += part[c*LDR + t];
    es[t] = a;
}

// u[which][b][i] = sum_e W[e*512+i] * es[b*512+e]
__global__ __launch_bounds__(256) void u_kernel(
    const float* __restrict__ W1, const float* __restrict__ W2,
    const double* __restrict__ es, double* __restrict__ u)
{
    const int t = blockIdx.x * 256 + threadIdx.x;  // 0..8191
    const int which = blockIdx.y;
    const float* W = which ? W2 : W1;
    const int b = t >> 9, i = t & 511;
    double a = 0.0;
    for (int e = 0; e < 512; ++e) a += (double)W[e*512 + i] * es[b*512 + e];
    u[which*8192 + t] = a;
}

__global__ __launch_bounds__(256) void c_kernel(
    const float* __restrict__ b1, const float* __restrict__ b2,
    const double* __restrict__ es, double* __restrict__ cd)
{
    __shared__ double red[256];
    const int b = blockIdx.x, t = threadIdx.x;
    double a = 0.0;
    for (int e = t; e < 512; e += 256) a += (double)(b1[e] + b2[e]) * es[b*512 + e];
    red[t] = a; __syncthreads();
    for (int s = 128; s > 0; s >>= 1) { if (t < s) red[t] += red[t+s]; __syncthreads(); }
    if (t == 0) cd[b] = red[0];
}

// Sinv[r] = 1 / ( X[r,:]·u1[b] + T[r,:]·u2[b] + c[b] ),  b = r%16, fp64
__global__ __launch_bounds__(256) void s_kernel(
    const float* __restrict__ X, const float* __restrict__ T,
    const double* __restrict__ u, const double* __restrict__ cd,
    float* __restrict__ Sinv)
{
    const int wave = threadIdx.x >> 6, lane = threadIdx.x & 63;
    const int r = blockIdx.x * 4 + wave;
    const int b = r & 15;
    const double* u1 = u + b*512;
    const double* u2 = u + 8192 + b*512;
    double a = 0.0;
    for (int e = lane*4; e < 512; e += 256) {
        float4 x  = *(const float4*)&X[r*512 + e];
        float4 t4 = *(const float4*)&T[r*512 + e];
        a += (double)x.x*u1[e] + (double)x.y*u1[e+1] + (double)x.z*u1[e+2] + (double)x.w*u1[e+3];
        a += (double)t4.x*u2[e] + (double)t4.y*u2[e+1] + (double)t4.z*u2[e+2] + (double)t4.w*u2[e+3];
    }
    #pragma unroll
    for (int off = 32; off > 0; off >>= 1) a += __shfl_down(a, off, 64);
    if (lane == 0) Sinv[r] = (float)(1.0 / (a + cd[b]));
}

extern "C" void kernel_launch(void* const* d_in, const int* in_sizes, int n_in,
                              void* d_out, int out_size, void* d_ws, size_t ws_size,
                              hipStream_t stream)
{
    const float* X   = (const float*)d_in[0];
    const float* Enc = (const float*)d_in[1];
    const float* T   = (const float*)d_in[2];
    const float* W1  = (const float*)d_in[3];
    const float* b1  = (const float*)d_in[4];
    const float* W2  = (const float*)d_in[5];
    const float* b2  = (const float*)d_in[6];
    const float* W3  = (const float*)d_in[7];
    const float* b3  = (const float*)d_in[8];
    float* out = (float*)d_out;

    char* w = (char*)d_ws;
    u16*    dvals_bf = (u16*)(w);                 // 16,777,216 B
    u16*    PT_bf    = (u16*)(w + 16777216);      // 16,777,216 B
    u16*    EncT_bf  = (u16*)(w + 33554432);      // 16,777,216 B
    u16*    HT_bf    = (u16*)(w + 50331648);      //  8,388,608 B
    double* part     = (double*)(w + 58720256);   //    524,288 B
    double* es       = (double*)(w + 59244544);   //     65,536 B
    double* u        = (double*)(w + 59310080);   //    131,072 B
    double* cd       = (double*)(w + 59441152);   //        128 B
    float*  Sinv     = (float*)(w + 59441280);    //     65,536 B

    dim3 blk(256);
    enct_kernel   <<<dim3(8, 16, 16), blk, 0, stream>>>(Enc, EncT_bf);
    encsum_partial<<<dim3(32, 8),     blk, 0, stream>>>(Enc, part);
    encsum_final  <<<dim3(32),        blk, 0, stream>>>(part, es);
    u_kernel      <<<dim3(32, 2),     blk, 0, stream>>>(W1, W2, es, u);
    c_kernel      <<<dim3(16),        blk, 0, stream>>>(b1, b2, es, cd);
    s_kernel      <<<dim3(4096),      blk, 0, stream>>>(X, T, u, cd, Sinv);

    gemm_bf16<1><<<dim3(4, 128, 1), blk, 0, stream>>>(X, T, W1, W2, W3, Enc, b1, b2, b3,
        Sinv, dvals_bf, PT_bf, EncT_bf, HT_bf, dvals_bf, out);
    gemm_bf16<2><<<dim3(8, 4, 16),  blk, 0, stream>>>(X, T, W1, W2, W3, Enc, b1, b2, b3,
        Sinv, dvals_bf, PT_bf, EncT_bf, HT_bf, PT_bf, out);
    gemm_bf16<3><<<dim3(4, 4, 16),  blk, 0, stream>>>(X, T, W1, W2, W3, Enc, b1, b2, b3,
        Sinv, dvals_bf, PT_bf, EncT_bf, HT_bf, HT_bf, out);
    gemm_bf16<4><<<dim3(4, 8, 16),  blk, 0, stream>>>(X, T, W1, W2, W3, Enc, b1, b2, b3,
        Sinv, dvals_bf, PT_bf, EncT_bf, HT_bf, dvals_bf, out);
}